// Round 25
// baseline (14464.024 us; speedup 1.0000x reference)
//
#include <hip/hip_runtime.h>
#include <cfloat>

#define NRW 32768
#define KC 4096
#define CD 256
#define HW 1024
#define CAP 48
#define WINH 5e-4f   // dot-space window: 2*gamma + delta + se_max <= 4.5e-4 < WINH
#define XPAD 258

typedef short bf16x8 __attribute__((ext_vector_type(8)));
typedef float f32x4 __attribute__((ext_vector_type(4)));

__device__ __forceinline__ unsigned short f2bf(float f) {  // RNE f32->bf16
  unsigned int u = __float_as_uint(f);
  u = (u + 0x7FFFu + ((u >> 16) & 1u)) >> 16;
  return (unsigned short)u;
}

// monotonic float->uint (order-preserving), and inverse [verified r24]
__device__ __forceinline__ unsigned flipf(float f) {
  unsigned u = __float_as_uint(f);
  return u ^ (unsigned)(((int)u >> 31) | 0x80000000);
}
__device__ __forceinline__ float unflipf(unsigned m) {
  return (m & 0x80000000u) ? __uint_as_float(m ^ 0x80000000u) : __uint_as_float(~m);
}

// direct global->LDS 16B async copy [verified r17-r24]
__device__ __forceinline__ void gl2lds16(const unsigned short* g, unsigned short* l) {
  __builtin_amdgcn_global_load_lds(
      (const __attribute__((address_space(1))) void*)(const void*)g,
      (__attribute__((address_space(3))) void*)(void*)l, 16, 0, 0);
}

// max across each 16-lane DPP row, pure VALU [verified r22-r24]
__device__ __forceinline__ float dppmax16(float v) {
  float t;
  t = __uint_as_float(__builtin_amdgcn_update_dpp(0, __float_as_uint(v), 0xB1, 0xF, 0xF, true));
  v = fmaxf(v, t);
  t = __uint_as_float(__builtin_amdgcn_update_dpp(0, __float_as_uint(v), 0x4E, 0xF, 0xF, true));
  v = fmaxf(v, t);
  t = __uint_as_float(__builtin_amdgcn_update_dpp(0, __float_as_uint(v), 0x141, 0xF, 0xF, true));
  v = fmaxf(v, t);
  t = __uint_as_float(__builtin_amdgcn_update_dpp(0, __float_as_uint(v), 0x140, 0xF, 0xF, true));
  v = fmaxf(v, t);
  return v;
}

// ---------- se[k] = np.sum(cb[k]**2) : numpy pairwise [verified]; zeroes nflg ----------
__global__ __launch_bounds__(256) void vq_se(const float* __restrict__ cb,
                                             float* __restrict__ se,
                                             int* __restrict__ nflg) {
#pragma clang fp contract(off)
  const int tid = threadIdx.x;
  if (blockIdx.x == 0 && tid == 0) *nflg = 0;
  const int g = tid >> 3;
  const int j = tid & 7;
  const int code = blockIdx.x * 32 + g;
  const float* e = cb + (size_t)code * CD;
  float half[2];
#pragma unroll
  for (int h = 0; h < 2; ++h) {
    const float* a = e + h * 128;
    float v = a[j];
    float r = v * v;
#pragma unroll
    for (int i = 1; i < 16; ++i) {
      float w = a[8 * i + j];
      float w2 = w * w;
      r = r + w2;
    }
    float l1 = r + __shfl_down(r, 1, 8);
    float l2 = l1 + __shfl_down(l1, 2, 8);
    float l3 = l2 + __shfl_down(l2, 4, 8);
    half[h] = l3;
  }
  if (j == 0) se[code] = half[0] + half[1];
}

// ---------- convert x -> xh[row][ch] bf16 (transpose, RNE) [verified] ----------
__global__ __launch_bounds__(256) void vq_cvt_x(const float* __restrict__ x,
                                                unsigned short* __restrict__ xh) {
  const int t = threadIdx.x;                  // channel
  const int b = blockIdx.x >> 4;
  const int hw0 = (blockIdx.x & 15) << 6;
  const float* src = x + ((size_t)b * CD + t) * HW + hw0;
  unsigned short* dst = xh + ((size_t)b * HW + hw0) * CD + t;
#pragma unroll
  for (int f = 0; f < 16; ++f) {
    const float4 v = *(const float4*)(src + 4 * f);
    dst[(size_t)(4 * f + 0) * CD] = f2bf(v.x);
    dst[(size_t)(4 * f + 1) * CD] = f2bf(v.y);
    dst[(size_t)(4 * f + 2) * CD] = f2bf(v.z);
    dst[(size_t)(4 * f + 3) * CD] = f2bf(v.w);
  }
}

// ---------- convert cb -> eh in B-FRAGMENT granule order [verified r19] ----------
// granule gid = c*512 + kb*64 + lane, lane = lq*16 + ll:
//   holds code c*16 + ll, channels [(kb*4+lq)*8, +8)
__global__ __launch_bounds__(256) void vq_cvt_e(const float* __restrict__ cb,
                                                unsigned short* __restrict__ eh) {
  const int gid = blockIdx.x * 256 + threadIdx.x;   // 131072 granules
  const int c  = gid >> 9;
  const int kb = (gid >> 6) & 7;
  const int lane = gid & 63;
  const int lq = lane >> 4, ll = lane & 15;
  const int code = (c << 4) | ll;
  const int c8 = kb * 4 + lq;
  const float* s = cb + (size_t)code * CD + (c8 << 3);
  uint4 v;
  v.x = (unsigned)f2bf(s[0]) | ((unsigned)f2bf(s[1]) << 16);
  v.y = (unsigned)f2bf(s[2]) | ((unsigned)f2bf(s[3]) << 16);
  v.z = (unsigned)f2bf(s[4]) | ((unsigned)f2bf(s[5]) << 16);
  v.w = (unsigned)f2bf(s[6]) | ((unsigned)f2bf(s[7]) << 16);
  *(uint4*)(eh + (size_t)gid * 8) = v;
}

// ---------- MFMA filter GEMM: wave-private chunks, ZERO loop barriers ----------
// 64 rows/block; wave w owns chunks c = w + 4i (16 codes each, interleaved), computes
// all 64 rows (4 m-tiles). Private double-buffered 8 KB LDS per wave. Collection =
// r24 packed dot|code + dump-time global re-filter.
__global__ __launch_bounds__(256, 2) void vq_gemm(const unsigned short* __restrict__ xh,
                                                  const unsigned short* __restrict__ eh,
                                                  int* __restrict__ cnt,
                                                  int* __restrict__ cand) {
  __shared__ unsigned short esb[4 * 2 * 4096];  // 64 KB: [wave][buf][4096 shorts]
  __shared__ unsigned candl[64 * CAP];          // 12 KB (packed dot|code)
  __shared__ int cntl[64];
  __shared__ unsigned maxsh[64];

  const int t = threadIdx.x;
  const int l = t & 63;
  const int w = t >> 6;
  const int lq = l >> 4;
  const int ll = l & 15;
  const int rowbase = blockIdx.x * 64;

  if (t < 64) { cntl[t] = 0; maxsh[t] = 0u; }

  // A fragments: 4 m-tiles x 8 kb = all 64 rows (128 VGPR)
  bf16x8 afr[4][8];
#pragma unroll
  for (int mt = 0; mt < 4; ++mt) {
    const unsigned short* ga = xh + (size_t)(rowbase + 16 * mt + ll) * CD + (lq << 3);
#pragma unroll
    for (int kb = 0; kb < 8; ++kb)
      afr[mt][kb] = *(const bf16x8*)(ga + (kb << 5));
  }

  // stage chunk (global granules c*512.. ) into private buffer buf
  unsigned short* const ebw = esb + w * 8192;
  auto STAGE = [&](int c, int buf) {
    const unsigned short* g = eh + (size_t)c * 4096;   // 512 granules x 8 shorts
    unsigned short* d = ebw + buf * 4096;
#pragma unroll
    for (int kb = 0; kb < 8; ++kb)
      gl2lds16(g + (size_t)(kb << 6) * 8, d + (kb << 9));
  };

  STAGE(w, 0);
  STAGE(w + 4, 1);
  __syncthreads();   // cntl/maxsh init visible to all waves

  float run[4][4], rr[4][4];
#pragma unroll
  for (int mt = 0; mt < 4; ++mt)
#pragma unroll
    for (int r = 0; r < 4; ++r) { run[mt][r] = -FLT_MAX; rr[mt][r] = FLT_MAX; }

#pragma unroll 1
  for (int i = 0; i < 64; ++i) {
    const int c = w + 4 * i;
    // wait own chunk i (8 loads); chunk i+1's 8 stay in flight
    if (i != 63) asm volatile("s_waitcnt vmcnt(8)" ::: "memory");
    else         asm volatile("s_waitcnt vmcnt(0)" ::: "memory");

    // read all B-fragments to registers (conflict-free: consecutive lanes, consecutive 16B)
    const unsigned short* eb = ebw + (i & 1) * 4096;
    bf16x8 bfr[8];
#pragma unroll
    for (int kb = 0; kb < 8; ++kb)
      bfr[kb] = *(const bf16x8*)&eb[((kb << 6) + l) * 8];
    asm volatile("s_waitcnt lgkmcnt(0)" ::: "memory");
    __builtin_amdgcn_sched_barrier(0);
    // buffer (i&1) now free: stage chunk i+2 into it (overlaps MFMAs below)
    if (i < 62) STAGE(w + 4 * (i + 2), i & 1);

    // 32 MFMA: 4 m-tiles x 8 kb
    f32x4 acc[4];
#pragma unroll
    for (int mt = 0; mt < 4; ++mt) acc[mt] = (f32x4){0.f, 0.f, 0.f, 0.f};
#pragma unroll
    for (int kb = 0; kb < 8; ++kb) {
#pragma unroll
      for (int mt = 0; mt < 4; ++mt)
        acc[mt] = __builtin_amdgcn_mfma_f32_16x16x32_bf16(afr[mt][kb], bfr[kb], acc[mt], 0, 0, 0);
    }

    // epilogue: running max; DPP tighten every 2nd chunk; collect packed (dot|code)
#pragma unroll
    for (int mt = 0; mt < 4; ++mt)
#pragma unroll
      for (int r = 0; r < 4; ++r)
        if (acc[mt][r] > run[mt][r]) run[mt][r] = acc[mt][r];
    if ((i & 1) == 0) {
#pragma unroll
      for (int mt = 0; mt < 4; ++mt)
#pragma unroll
        for (int r = 0; r < 4; ++r) rr[mt][r] = dppmax16(run[mt][r]) - WINH;
    }
    const unsigned codebits = (unsigned)((c << 4) + ll);
#pragma unroll
    for (int mt = 0; mt < 4; ++mt)
#pragma unroll
      for (int r = 0; r < 4; ++r) {
        if (acc[mt][r] >= rr[mt][r]) {
          const int rowloc = 16 * mt + (lq << 2) + r;
          const int pos = atomicAdd(&cntl[rowloc], 1);
          if (pos < CAP) candl[rowloc * CAP + pos] = (flipf(acc[mt][r]) & 0xFFFFF000u) | codebits;
        }
      }
  }

  // contribute final maxes to maxsh (cross-wave global max per row)
  {
#pragma unroll
    for (int mt = 0; mt < 4; ++mt)
#pragma unroll
      for (int r = 0; r < 4; ++r) {
        const float f = dppmax16(run[mt][r]);
        if (ll == 0) atomicMax(&maxsh[16 * mt + (lq << 2) + r], flipf(f));
      }
  }
  __syncthreads();

  // dump: re-filter against FINAL threshold gm - WINH (one-quantum slack), compact [r24]
  if (t < 64) {
    const int cn = cntl[t];
    const float gm = unflipf(maxsh[t]);
    const unsigned tp = flipf(gm - WINH) & 0xFFFFF000u;
    const int lim = cn < CAP ? cn : CAP;
    int kept = 0;
    for (int pos = 0; pos < lim; ++pos) {
      const unsigned pk = candl[t * CAP + pos];
      if ((pk & 0xFFFFF000u) + 0x1000u >= tp)
        cand[(size_t)(rowbase + t) * CAP + (kept++)] = (int)(pk & 0xFFFu);
    }
    cnt[rowbase + t] = (cn > CAP) ? cn : kept;
  }
}

// ---------- np-exact recheck: 32 rows/block, line-perfect staging, cn==1 shortcut [r23/r24] ----------
__global__ __launch_bounds__(256, 2) void vq_recheck(const float* __restrict__ x,
                                                     const float* __restrict__ cb,
                                                     const float* __restrict__ se,
                                                     const int* __restrict__ cnt,
                                                     const int* __restrict__ cand,
                                                     float* __restrict__ outids,
                                                     int* __restrict__ flg,
                                                     int* __restrict__ nflg) {
#pragma clang fp contract(off)
  __shared__ float xr[32 * XPAD];    // 33 KB
  __shared__ float sxs[32];
  const int t = threadIdx.x;
  const int rowbase = blockIdx.x * 32;
  const int b = rowbase >> 10, hw0 = rowbase & 1023;

  {
    const float* px = x + ((size_t)b * CD + t) * HW + hw0;
#pragma unroll
    for (int f = 0; f < 8; ++f) {
      const float4 v = *(const float4*)(px + 4 * f);
      xr[(4 * f + 0) * XPAD + t] = v.x;
      xr[(4 * f + 1) * XPAD + t] = v.y;
      xr[(4 * f + 2) * XPAD + t] = v.z;
      xr[(4 * f + 3) * XPAD + t] = v.w;
    }
  }
  __syncthreads();

  {
    const int g = t >> 3, j = t & 7;
    float half[2];
#pragma unroll
    for (int h = 0; h < 2; ++h) {
      const float* a = xr + g * XPAD + h * 128;
      float v = a[j];
      float r = v * v;
#pragma unroll
      for (int i = 1; i < 16; ++i) {
        float ww = a[8 * i + j];
        float w2 = ww * ww;
        r = r + w2;
      }
      float l1 = r + __shfl_down(r, 1, 8);
      float l2 = l1 + __shfl_down(l1, 2, 8);
      float l3 = l2 + __shfl_down(l2, 4, 8);
      half[h] = l3;
    }
    if (j == 0) sxs[g] = half[0] + half[1];
  }
  __syncthreads();

  {
    const int g = t >> 3, j = t & 7;
    const int row = rowbase + g;
    const int cn = cnt[row];
    if (cn > CAP) {
      if (j == 0) { const int p = atomicAdd(nflg, 1); flg[p] = row; }
    } else if (cn == 1) {
      if (j == 0) outids[row] = (float)cand[(size_t)row * CAP];
    } else {
      float bv = FLT_MAX;
      int bi = 0x7FFFFFFF;
      const float sx = sxs[g];
      const float* xrow = xr + g * XPAD;
      for (int c = j; c < cn; c += 8) {
        const int k = cand[(size_t)row * CAP + c];
        const float* ek = cb + (size_t)k * CD;
        float a0 = 0.f, a1 = 0.f, a2 = 0.f, a3 = 0.f;
        for (int B = 0; B < 16; ++B)
          for (int jj = 3; jj >= 0; --jj) {
            const int c0 = 16 * B + 4 * jj;
            float p0 = xrow[c0 + 0] * ek[c0 + 0]; a0 = a0 + p0;
            float p1 = xrow[c0 + 1] * ek[c0 + 1]; a1 = a1 + p1;
            float p2 = xrow[c0 + 2] * ek[c0 + 2]; a2 = a2 + p2;
            float p3 = xrow[c0 + 3] * ek[c0 + 3]; a3 = a3 + p3;
          }
        const float dot = (a0 + a1) + (a2 + a3);
        const float dist = (se[k] + sx) - 2.0f * dot;
        if (dist < bv || (dist == bv && k < bi)) { bv = dist; bi = k; }
      }
#pragma unroll
      for (int off = 1; off < 8; off <<= 1) {
        const float ov = __shfl_xor(bv, off, 8);
        const int oi = __shfl_xor(bi, off, 8);
        if (ov < bv || (ov == bv && oi < bi)) { bv = ov; bi = oi; }
      }
      if (j == 0) outids[row] = (float)bi;
    }
  }
}

// ---------- full-row np-exact fallback for overflow rows [verified] ----------
__global__ __launch_bounds__(256) void vq_fallback(const float* __restrict__ x,
                                                   const float* __restrict__ cb,
                                                   const float* __restrict__ se,
                                                   const int* __restrict__ flg,
                                                   const int* __restrict__ nflg,
                                                   float* __restrict__ outids) {
#pragma clang fp contract(off)
  __shared__ float xr[256];
  __shared__ float sxv;
  __shared__ float rv[256];
  __shared__ int ri[256];
  const int t = threadIdx.x;
  const int nf = *nflg;
  for (int fi = blockIdx.x; fi < nf; fi += gridDim.x) {
    const int row = flg[fi];
    const int b = row >> 10, hw = row & 1023;
    __syncthreads();
    xr[t] = x[((size_t)b * CD + t) * HW + hw];
    __syncthreads();
    if (t == 0) {
      float half[2];
      for (int h = 0; h < 2; ++h) {
        float racc[8];
        for (int j = 0; j < 8; ++j) { const float v = xr[h * 128 + j]; racc[j] = v * v; }
        for (int i = 1; i < 16; ++i)
          for (int j = 0; j < 8; ++j) {
            const float v = xr[h * 128 + 8 * i + j];
            const float v2 = v * v;
            racc[j] = racc[j] + v2;
          }
        half[h] = ((racc[0] + racc[1]) + (racc[2] + racc[3])) +
                  ((racc[4] + racc[5]) + (racc[6] + racc[7]));
      }
      sxv = half[0] + half[1];
    }
    __syncthreads();
    float bv = FLT_MAX;
    int bi = 0x7FFFFFFF;
    for (int j = 0; j < 16; ++j) {
      const int k = j * 256 + t;
      const float* ek = cb + (size_t)k * CD;
      float a0 = 0.f, a1 = 0.f, a2 = 0.f, a3 = 0.f;
      for (int B = 0; B < 16; ++B)
        for (int jj = 3; jj >= 0; --jj) {
          const int c0 = 16 * B + 4 * jj;
          float p0 = xr[c0 + 0] * ek[c0 + 0]; a0 = a0 + p0;
          float p1 = xr[c0 + 1] * ek[c0 + 1]; a1 = a1 + p1;
          float p2 = xr[c0 + 2] * ek[c0 + 2]; a2 = a2 + p2;
          float p3 = xr[c0 + 3] * ek[c0 + 3]; a3 = a3 + p3;
        }
      const float dot = (a0 + a1) + (a2 + a3);
      const float dist = (se[k] + sxv) - 2.0f * dot;
      if (dist < bv || (dist == bv && k < bi)) { bv = dist; bi = k; }
    }
    rv[t] = bv; ri[t] = bi;
    __syncthreads();
    for (int off = 128; off > 0; off >>= 1) {
      if (t < off) {
        if (rv[t + off] < rv[t] || (rv[t + off] == rv[t] && ri[t + off] < ri[t])) {
          rv[t] = rv[t + off]; ri[t] = ri[t + off];
        }
      }
      __syncthreads();
    }
    if (t == 0) outids[row] = (float)ri[0];
  }
}

// ---------- emb gather [verified] ----------
__global__ __launch_bounds__(256) void vq_emb_out(const float* __restrict__ outids,
                                                  const float* __restrict__ cb,
                                                  float* __restrict__ out) {
  const int bx = blockIdx.x;
  const int b = bx >> 10;
  const int rem = bx & 1023;
  const int c = rem >> 2;
  const int q = rem & 3;
  const int hw = q * 256 + threadIdx.x;
  const int id = (int)outids[b * HW + hw];
  out[((size_t)(b * CD + c)) * HW + hw] = cb[(size_t)id * CD + c];
}

extern "C" void kernel_launch(void* const* d_in, const int* in_sizes, int n_in,
                              void* d_out, int out_size, void* d_ws, size_t ws_size,
                              hipStream_t stream) {
  const float* x  = (const float*)d_in[0];   // (32,256,32,32) f32
  const float* cb = (const float*)d_in[1];   // (4096,256) f32
  float* out = (float*)d_out;                // [0..32767]=ids, [32768..]=emb

  float* se = (float*)d_ws;                  // 16 KB

  // scratch inside the emb region (8,388,608 floats), overwritten last by gather
  float* sc = out + NRW;
  unsigned short* xh = (unsigned short*)sc;              // 16.8 MB
  unsigned short* eh = (unsigned short*)(sc + 4194304);  // 2.1 MB (fragment-order granules)
  int*   cnt  = (int*)(sc + 4751360);                    // 32,768
  int*   flg  = (int*)(sc + 4784128);                    // 32,768
  int*   nflg = (int*)(sc + 4816896);                    // 1
  int*   cand = (int*)(sc + 4816960);                    // 32768*CAP ints

  vq_se<<<KC / 32, 256, 0, stream>>>(cb, se, nflg);
  vq_cvt_x<<<512, 256, 0, stream>>>(x, xh);
  vq_cvt_e<<<512, 256, 0, stream>>>(cb, eh);
  vq_gemm<<<NRW / 64, 256, 0, stream>>>(xh, eh, cnt, cand);
  vq_recheck<<<NRW / 32, 256, 0, stream>>>(x, cb, se, cnt, cand, out, flg, nflg);
  vq_fallback<<<512, 256, 0, stream>>>(x, cb, se, flg, nflg, out);
  vq_emb_out<<<32768, 256, 0, stream>>>(out, cb, out + NRW);
}